// Round 6
// baseline (472.618 us; speedup 1.0000x reference)
//
#include <hip/hip_runtime.h>

#define N_DIS 25000
#define N_MIR 25000
#define NN    50000
#define E_NUM 600000
#define EMB   128

typedef __attribute__((ext_vector_type(8))) short short8v;   // 8 bf16 payloads (4 VGPR)
typedef __attribute__((ext_vector_type(4))) float floatx4;   // MFMA acc (4 VGPR)

// v_mfma_f32_16x16x32_bf16 via inline asm: robust to builtin vector-elt-type conventions.
__device__ __forceinline__ floatx4 mfma_bf16_16x16x32(short8v a, short8v b, floatx4 c) {
    asm("v_mfma_f32_16x16x32_bf16 %0, %1, %2, %0" : "+v"(c) : "v"(a), "v"(b));
    return c;
}

// bf16 <-> f32 via bit ops (no hip_bf16.h; no bf16 types in any kernel signature)
__device__ __forceinline__ float us2f(unsigned short u) {
    return __uint_as_float(((unsigned)u) << 16);
}
__device__ __forceinline__ unsigned short f2us(float f) {
    unsigned u = __float_as_uint(f);
    unsigned r = ((u >> 16) & 1u) + 0x7FFFu;  // round-to-nearest-even
    u += r;
    return (unsigned short)(u >> 16);
}
__device__ __forceinline__ float loadf(const void* p, size_t i, bool isbf) {
    if (isbf) return us2f(((const unsigned short*)p)[i]);
    return ((const float*)p)[i];
}

// ---------------- init: zero counts + flag ----------------
__global__ __launch_bounds__(256) void gs_zero(int* counts, int* flags) {
    int i = blockIdx.x * blockDim.x + threadIdx.x;
    if (i < NN) counts[i] = 0;
    if (i < 8) flags[i] = 0;
}

__global__ __launch_bounds__(64) void gs_setflag(int* flags, int v) {
    if (threadIdx.x == 0) flags[0] = v;
}

// dtype probe: bf16 data -> low-16 exponent near 127 (plausible w.p. ~0.99);
// f32 data -> low 16 bits are mantissa junk (plausible w.p. ~0.07). flags[0] += count.
__global__ __launch_bounds__(256) void gs_probe(const void* x, int* flags) {
    const unsigned* u = (const unsigned*)x;
    unsigned w = u[threadIdx.x];
    int e = (int)((w >> 7) & 0xFF);
    if (e >= 118 && e <= 135) atomicAdd(&flags[0], 1);
}

// ---------------- weight prep: WT[c][k] = split-bf16 of W[k][c], zero-padded to Kp ------
__global__ __launch_bounds__(256) void gs_prepw(const void* Wd, const void* Wm,
                                                const void* Ws1, const void* Wn1,
                                                const void* Ws2, const void* Wn2,
                                                const int* flags, unsigned short* wt) {
    const bool isbf = flags[0] > 128;
    const int t = threadIdx.x;
    const int w = blockIdx.x >> 2;
    const int cq = (blockIdx.x & 3) * 32;
    const void* W;
    unsigned short* oh;
    unsigned short* ol;
    int K, Kp;
    if (w == 0)      { W = Wd;  oh = wt + 0;      ol = wt + 49152;  K = 383; Kp = 384; }
    else if (w == 1) { W = Wm;  oh = wt + 98304;  ol = wt + 163840; K = 495; Kp = 512; }
    else if (w == 2) { W = Ws1; oh = wt + 229376; ol = wt + 245760; K = 128; Kp = 128; }
    else if (w == 3) { W = Wn1; oh = wt + 262144; ol = wt + 278528; K = 128; Kp = 128; }
    else if (w == 4) { W = Ws2; oh = wt + 294912; ol = wt + 311296; K = 128; Kp = 128; }
    else             { W = Wn2; oh = wt + 327680; ol = wt + 344064; K = 128; Kp = 128; }
    for (int c = cq; c < cq + 32; ++c) {
        for (int k = t; k < Kp; k += 256) {
            float x = (k < K) ? loadf(W, (size_t)k * EMB + c, isbf) : 0.f;
            unsigned short h = f2us(x);
            oh[(size_t)c * Kp + k] = h;
            ol[(size_t)c * Kp + k] = f2us(x - us2f(h));
        }
    }
}

// ---------------- CSR build ----------------
__global__ __launch_bounds__(256) void gs_count(const int* dst, int* counts) {
    int e = blockIdx.x * blockDim.x + threadIdx.x;
    if (e < E_NUM) {
        unsigned d = (unsigned)dst[e];
        if (d < (unsigned)NN) atomicAdd(&counts[d], 1);
    }
}

__global__ __launch_bounds__(256) void gs_scan1(const int* counts, int* row_start, int* bsums) {
    __shared__ int tsum[256];
    const int t = threadIdx.x;
    const int base = blockIdx.x * 1024 + t * 4;
    int v0 = (base + 0 < NN) ? counts[base + 0] : 0;
    int v1 = (base + 1 < NN) ? counts[base + 1] : 0;
    int v2 = (base + 2 < NN) ? counts[base + 2] : 0;
    int v3 = (base + 3 < NN) ? counts[base + 3] : 0;
    int s = v0 + v1 + v2 + v3;
    tsum[t] = s;
    __syncthreads();
    for (int off = 1; off < 256; off <<= 1) {
        int xv = 0;
        if (t >= off) xv = tsum[t - off];
        __syncthreads();
        tsum[t] += xv;
        __syncthreads();
    }
    int excl = tsum[t] - s;
    if (base + 0 < NN) row_start[base + 0] = excl;
    excl += v0;
    if (base + 1 < NN) row_start[base + 1] = excl;
    excl += v1;
    if (base + 2 < NN) row_start[base + 2] = excl;
    excl += v2;
    if (base + 3 < NN) row_start[base + 3] = excl;
    if (t == 255) bsums[blockIdx.x] = tsum[255];
}

__global__ __launch_bounds__(64) void gs_scan2(int* bsums, int* row_start, int nb) {
    if (threadIdx.x == 0) {
        int run = 0;
        for (int i = 0; i < nb; ++i) {
            int v = bsums[i];
            bsums[i] = run;
            run += v;
        }
        row_start[NN] = run;
    }
}

__global__ __launch_bounds__(256) void gs_scan3(int* row_start, int* cursor, const int* bsums) {
    const int t = threadIdx.x;
    const int base = blockIdx.x * 1024 + t * 4;
    const int add = bsums[blockIdx.x];
    for (int i = 0; i < 4; ++i) {
        int idx = base + i;
        if (idx < NN) {
            int v = row_start[idx] + add;
            row_start[idx] = v;
            cursor[idx] = v;
        }
    }
}

__global__ __launch_bounds__(256) void gs_scatter(const int* src, const int* dst, int* cursor,
                                                  int* eidx) {
    int e = blockIdx.x * blockDim.x + threadIdx.x;
    if (e < E_NUM) {
        unsigned d = (unsigned)dst[e];
        unsigned sv = (unsigned)src[e];
        if (d < (unsigned)NN && sv < (unsigned)NN) {
            int p = atomicAdd(&cursor[d], 1);
            eidx[p] = (int)sv;
        }
    }
}

// ---------------- mean aggregation: agg[n] = mean_{e in CSR[n]} x[eidx[e]] ----------------
__global__ __launch_bounds__(256) void gs_agg(const float* __restrict__ x,
                                              const int* __restrict__ row_start,
                                              const int* __restrict__ eidx,
                                              float* __restrict__ agg) {
    const int t = threadIdx.x;
    const int row = blockIdx.x * 8 + (t >> 5);
    const int tc = (t & 31) * 4;
    if (row >= NN) return;
    const int s0 = row_start[row];
    const int s1 = row_start[row + 1];
    float a0x = 0.f, a0y = 0.f, a0z = 0.f, a0w = 0.f;
    float a1x = 0.f, a1y = 0.f, a1z = 0.f, a1w = 0.f;
    int e = s0;
    for (; e + 1 < s1; e += 2) {
        int sa = eidx[e];
        int sb = eidx[e + 1];
        float4 va = *(const float4*)&x[(size_t)sa * EMB + tc];
        float4 vb = *(const float4*)&x[(size_t)sb * EMB + tc];
        a0x += va.x; a0y += va.y; a0z += va.z; a0w += va.w;
        a1x += vb.x; a1y += vb.y; a1z += vb.z; a1w += vb.w;
    }
    if (e < s1) {
        int sa = eidx[e];
        float4 va = *(const float4*)&x[(size_t)sa * EMB + tc];
        a0x += va.x; a0y += va.y; a0z += va.z; a0w += va.w;
    }
    float inv = (s1 > s0) ? 1.f / (float)(s1 - s0) : 0.f;
    float4 o;
    o.x = (a0x + a1x) * inv;
    o.y = (a0y + a1y) * inv;
    o.z = (a0z + a1z) * inv;
    o.w = (a0w + a1w) * inv;
    *(float4*)&agg[(size_t)row * EMB + tc] = o;
}

// ---------------- MFMA GEMM with register-prefetch (T14) ----------------
// BM=64 rows/block, 256 threads = 4 waves in 2x2 (each wave: 32 rows x 64 cols).
// KC=64 per chunk. LDS 48KB single-buffer (3 blocks/CU), XOR-swizzled (conflict-free, r5).
// Pipeline: FETCH(ch+1) raw global->reg issued before compute(ch); WRITE(ch) after barrier
// finds vmcnt satisfied -> global latency hides under MFMA.
// Split math: x = xh + xl (trunc split), w = wh + wl; D += xh*wh + xl*wh + xh*wl.
__global__ __launch_bounds__(256, 3) void gs_mm(
    const void* __restrict__ Xa, int Ka, const unsigned short* __restrict__ WAh,
    const unsigned short* __restrict__ WAl, int KpA, const void* __restrict__ ba,
    const void* __restrict__ Xb, int Kb, const unsigned short* __restrict__ WBh,
    const unsigned short* __restrict__ WBl, int KpB, const void* __restrict__ bb,
    int splitB, int Ma, int Mb,
    const float* __restrict__ X2, const unsigned short* __restrict__ W2h,
    const unsigned short* __restrict__ W2l,
    const int* __restrict__ flags, float* __restrict__ out, int x1_dyn, int do_relu) {
    __shared__ __align__(16) unsigned char sm[49152];
    unsigned char* smXH = sm;           //  8 KB: Xh [64 rows][128 B]
    unsigned char* smXL = sm + 8192;    //  8 KB: Xl
    unsigned char* smWH = sm + 16384;   // 16 KB: Wh [128 cols][128 B]
    unsigned char* smWL = sm + 32768;   // 16 KB: Wl
    const bool isbf = flags[0] > 128;
    const int t = threadIdx.x;
    const bool sideB = (int)blockIdx.x >= splitB;
    const void* X1 = sideB ? Xb : Xa;
    const unsigned short* W1h = sideB ? WBh : WAh;
    const unsigned short* W1l = sideB ? WBl : WAl;
    const int K1 = sideB ? Kb : Ka;
    const int Kp1 = sideB ? KpB : KpA;
    const void* bias = sideB ? bb : ba;
    const int M = sideB ? Mb : Ma;
    const int r0 = (sideB ? ((int)blockIdx.x - splitB) : (int)blockIdx.x) * 64;
    float* outb = out + (sideB ? (size_t)Ma * EMB : 0);
    const bool x1bf = (x1_dyn != 0) && isbf;

    const int l = t & 63;
    const int wv = t >> 6;
    const int wr = wv >> 1, wc = wv & 1;  // 2x2 wave grid
    const int lr = l & 15, lg = l >> 4;   // fragment lane decomposition

    floatx4 acc[2][4];
#pragma unroll
    for (int rt = 0; rt < 2; ++rt)
#pragma unroll
        for (int ct = 0; ct < 4; ++ct) acc[rt][ct] = (floatx4){0.f, 0.f, 0.f, 0.f};

    const int nch1 = (K1 + 63) >> 6;
    const int totch = nch1 + (X2 ? 2 : 0);

    // staging thread mapping
    const int srX = t >> 2;          // X stage: row 0..63
    const int skX = (t & 3) << 4;    // X stage: k base (16 k per thread)
    const int scW = t >> 1;          // W stage: col 0..127
    const int skW = (t & 1) << 5;    // W stage: k base (32 k per thread)

    // prefetch registers (raw bits; no dependent ALU on the loads)
    unsigned xr[16];
    short8v wfh[4], wfl[4];

    // current-prefetch chunk descriptor
    const void* cX;
    const unsigned short* cWh;
    const unsigned short* cWl;
    int ck0, cK, cKp;
    bool cxbf, cvec;
    auto DESC = [&](int ch) {
        if (ch < nch1) {
            cX = X1; cWh = W1h; cWl = W1l; ck0 = ch << 6; cK = K1; cKp = Kp1; cxbf = x1bf;
        } else {
            cX = (const void*)X2; cWh = W2h; cWl = W2l;
            ck0 = (ch - nch1) << 6; cK = 128; cKp = 128; cxbf = false;
        }
        cvec = (!cxbf) && (cK == 128);
    };

    auto FETCH = [&]() {
        const int gr = r0 + srX;
        if (cvec) {
            if (gr < M) {
                const float* p = &((const float*)cX)[(size_t)gr * 128 + ck0 + skX];
#pragma unroll
                for (int q = 0; q < 4; ++q) {
                    float4 v = *(const float4*)(p + (q << 2));
                    xr[q * 4 + 0] = __float_as_uint(v.x);
                    xr[q * 4 + 1] = __float_as_uint(v.y);
                    xr[q * 4 + 2] = __float_as_uint(v.z);
                    xr[q * 4 + 3] = __float_as_uint(v.w);
                }
            } else {
#pragma unroll
                for (int j = 0; j < 16; ++j) xr[j] = 0u;
            }
        } else {
#pragma unroll
            for (int j = 0; j < 16; ++j) {
                int gk = ck0 + skX + j;
                unsigned v = 0u;
                if (gr < M && gk < cK)
                    v = cxbf ? (unsigned)((const unsigned short*)cX)[(size_t)gr * cK + gk]
                             : ((const unsigned*)cX)[(size_t)gr * cK + gk];
                xr[j] = v;
            }
        }
        {
            const unsigned short* ph = cWh + (size_t)scW * cKp + ck0 + skW;
#pragma unroll
            for (int g = 0; g < 4; ++g) wfh[g] = *(const short8v*)(ph + (g << 3));
            if (!isbf) {
                const unsigned short* pl = cWl + (size_t)scW * cKp + ck0 + skW;
#pragma unroll
                for (int g = 0; g < 4; ++g) wfl[g] = *(const short8v*)(pl + (g << 3));
            }
        }
    };

    auto WRITE = [&](bool xbf) {
        // X: trunc split (hi = top 16 bits; lo = rne(x - hi)); bf16 input: hi only
        const int rowoff = srX << 7;
        const int swz = (srX & 7) << 4;
#pragma unroll
        for (int g = 0; g < 2; ++g) {
            short8v vh, vl;
#pragma unroll
            for (int e = 0; e < 8; ++e) {
                unsigned u = xr[(g << 3) + e];
                if (xbf) {
                    vh[e] = (short)u;
                    vl[e] = 0;
                } else {
                    unsigned short h = (unsigned short)(u >> 16);
                    vh[e] = (short)h;
                    vl[e] = (short)f2us(__uint_as_float(u) - us2f(h));
                }
            }
            const int off = rowoff + ((((skX << 1) + (g << 4))) ^ swz);
            *(short8v*)(smXH + off) = vh;
            if (!xbf) *(short8v*)(smXL + off) = vl;
        }
        // W: pure copies
        const int coff = scW << 7;
        const int csw = (scW & 7) << 4;
#pragma unroll
        for (int g = 0; g < 4; ++g) {
            const int off = coff + ((((skW << 1) + (g << 4))) ^ csw);
            *(short8v*)(smWH + off) = wfh[g];
            if (!isbf) *(short8v*)(smWL + off) = wfl[g];
        }
    };

    DESC(0);
    FETCH();
    for (int ch = 0; ch < totch; ++ch) {
        const bool xbf = cxbf;  // flags of the chunk now in registers
        __syncthreads();        // previous chunk's compute fully consumed LDS
        WRITE(xbf);             // vmcnt satisfied (loads issued one iteration ago)
        __syncthreads();
        if (ch + 1 < totch) {
            DESC(ch + 1);
            FETCH();            // issue next chunk's loads; latency hides under MFMA below
        }
        // ---- compute: 2 k-steps x (2 row-tiles x 4 col-tiles), split MFMA ----
        const bool skip_xl = xbf;   // X was bf16 -> Xl == 0
        const bool skip_wl = isbf;  // W was bf16 -> Wl == 0
#pragma unroll
        for (int ks = 0; ks < 2; ++ks) {
            const int kbyte = (ks << 6) + (lg << 4);
            short8v ah[2], al[2];
#pragma unroll
            for (int rt = 0; rt < 2; ++rt) {
                const int row = wr * 32 + rt * 16 + lr;
                const int off = (row << 7) + (kbyte ^ ((row & 7) << 4));
                ah[rt] = *(const short8v*)(smXH + off);
                if (!skip_xl) al[rt] = *(const short8v*)(smXL + off);
            }
#pragma unroll
            for (int ct = 0; ct < 4; ++ct) {
                const int col = wc * 64 + ct * 16 + lr;
                const int boff = (col << 7) + (kbyte ^ ((col & 7) << 4));
                short8v bh = *(const short8v*)(smWH + boff);
                acc[0][ct] = mfma_bf16_16x16x32(ah[0], bh, acc[0][ct]);
                acc[1][ct] = mfma_bf16_16x16x32(ah[1], bh, acc[1][ct]);
                if (!skip_xl) {
                    acc[0][ct] = mfma_bf16_16x16x32(al[0], bh, acc[0][ct]);
                    acc[1][ct] = mfma_bf16_16x16x32(al[1], bh, acc[1][ct]);
                }
                if (!skip_wl) {
                    short8v bl = *(const short8v*)(smWL + boff);
                    acc[0][ct] = mfma_bf16_16x16x32(ah[0], bl, acc[0][ct]);
                    acc[1][ct] = mfma_bf16_16x16x32(ah[1], bl, acc[1][ct]);
                }
            }
        }
    }

    // ---- epilogue: D[i][j] lane map (m89): j = lane&15, i = 4*(lane>>4)+reg ----
#pragma unroll
    for (int ct = 0; ct < 4; ++ct) {
        const int col = wc * 64 + ct * 16 + lr;
        const float bbv = loadf(bias, col, isbf);
#pragma unroll
        for (int rt = 0; rt < 2; ++rt) {
#pragma unroll
            for (int rr = 0; rr < 4; ++rr) {
                const int row = r0 + wr * 32 + rt * 16 + (lg << 2) + rr;
                if (row < M) {
                    float v = acc[rt][ct][rr] + bbv;
                    if (do_relu) v = v > 0.f ? v : 0.f;
                    outb[(size_t)row * EMB + col] = v;
                }
            }
        }
    }
}

extern "C" __attribute__((visibility("default"))) void kernel_launch(
    void* const* d_in, const int* in_sizes, int n_in, void* d_out, int out_size, void* d_ws,
    size_t ws_size, hipStream_t stream) {
    // ---- ordering + dtype from in_sizes[0] (d_features in dict order, W_d if sorted) ----
    int iDF = 0, iMF = 1, iSRC = 2, iDST = 3, iWD = 4, iBD = 5, iWM = 6, iBM = 7;
    int iWS1 = 8, iWN1 = 9, iB1 = 10, iWS2 = 11, iWN2 = 12, iB2 = 13;
    long u0 = in_sizes ? (long)in_sizes[0] : 9575000L;
    int dt = -1;  // -1 unknown (probe), 0 f32, 1 bf16
    if (u0 == 49024L || u0 == 98048L || u0 == 196096L) {
        iWD = 0; iWM = 1; iWN1 = 2; iWN2 = 3; iWS1 = 4; iWS2 = 5;
        iB1 = 6; iB2 = 7; iBD = 8; iBM = 9; iDF = 10; iDST = 11; iMF = 12; iSRC = 13;
        if (u0 == 98048L) dt = 1;
        else if (u0 == 196096L) dt = 0;
    } else {
        if (u0 == 19150000L) dt = 1;       // bytes, bf16
        else if (u0 == 38300000L) dt = 0;  // bytes, f32
    }
    const void* d_features = d_in[iDF];
    const void* m_features = d_in[iMF];
    const int* src = (const int*)d_in[iSRC];
    const int* dst = (const int*)d_in[iDST];
    const void* W_d = d_in[iWD];
    const void* b_d = d_in[iBD];
    const void* W_m = d_in[iWM];
    const void* b_m = d_in[iBM];
    const void* W_self1 = d_in[iWS1];
    const void* W_neigh1 = d_in[iWN1];
    const void* b1 = d_in[iB1];
    const void* W_self2 = d_in[iWS2];
    const void* W_neigh2 = d_in[iWN2];
    const void* b2v = d_in[iB2];

    // ---- workspace layout (~54.92 MB) ----
    char* w = (char*)d_ws;
    int* flags = (int*)(w + 0);            //        64 B
    int* counts = (int*)(w + 64);          //   200,000 B
    int* row_start = (int*)(w + 200064);   //   200,004 B (pad to 400128)
    int* cursor = (int*)(w + 400128);      //   200,000 B
    int* bsums = (int*)(w + 600128);       //       256 B
    int* eidx = (int*)(w + 600384);        // 2,400,000 B (pad to 3000448)
    unsigned short* wt = (unsigned short*)(w + 3000448);  // 720,896 B of split-bf16 WT panels
    unsigned short* wt_hd = wt + 0;
    unsigned short* wt_ld = wt + 49152;
    unsigned short* wt_hm = wt + 98304;
    unsigned short* wt_lm = wt + 163840;
    unsigned short* wt_hs1 = wt + 229376;
    unsigned short* wt_ls1 = wt + 245760;
    unsigned short* wt_hn1 = wt + 262144;
    unsigned short* wt_ln1 = wt + 278528;
    unsigned short* wt_hs2 = wt + 294912;
    unsigned short* wt_ls2 = wt + 311296;
    unsigned short* wt_hn2 = wt + 327680;
    unsigned short* wt_ln2 = wt + 344064;
    float* hF = (float*)(w + 3721344);     // 25,600,000 B
    float* h1F = (float*)(w + 29321344);   // 25,600,000 B -> ends 54,921,344
    // agg scratch: layer1 agg -> d_out (overwritten later); layer2 agg -> hF (dead after L1)

    const int NB_SCAN = (NN + 1023) / 1024;  // 49
    const int EB = (E_NUM + 255) / 256;      // 2344
    const int ZB = (NN + 255) / 256;         // 196

    // init + dtype resolution (flags[0] > 128 => bf16)
    hipLaunchKernelGGL(gs_zero, dim3(ZB), dim3(256), 0, stream, counts, flags);
    if (dt == 1)
        hipLaunchKernelGGL(gs_setflag, dim3(1), dim3(64), 0, stream, flags, 1000);
    else if (dt == 0)
        hipLaunchKernelGGL(gs_setflag, dim3(1), dim3(64), 0, stream, flags, 0);
    else
        hipLaunchKernelGGL(gs_probe, dim3(1), dim3(256), 0, stream, d_features, flags);

    // weight prep (after dtype resolution)
    hipLaunchKernelGGL(gs_prepw, dim3(24), dim3(256), 0, stream, W_d, W_m, W_self1, W_neigh1,
                       W_self2, W_neigh2, flags, wt);

    // CSR build
    hipLaunchKernelGGL(gs_count, dim3(EB), dim3(256), 0, stream, dst, counts);
    hipLaunchKernelGGL(gs_scan1, dim3(NB_SCAN), dim3(256), 0, stream, counts, row_start, bsums);
    hipLaunchKernelGGL(gs_scan2, dim3(1), dim3(64), 0, stream, bsums, row_start, NB_SCAN);
    hipLaunchKernelGGL(gs_scan3, dim3(NB_SCAN), dim3(256), 0, stream, row_start, cursor, bsums);
    hipLaunchKernelGGL(gs_scatter, dim3(EB), dim3(256), 0, stream, src, dst, cursor, eidx);

    // both projections in ONE dispatch (block-split): blocks [0,391) disease, [391,782) mirna
    const int PBd = (N_DIS + 63) / 64;  // 391
    hipLaunchKernelGGL(gs_mm, dim3(2 * PBd), dim3(256), 0, stream,
                       d_features, 383, wt_hd, wt_ld, 384, b_d,
                       m_features, 495, wt_hm, wt_lm, 512, b_m,
                       PBd, N_DIS, N_MIR,
                       (const float*)nullptr, (const unsigned short*)nullptr,
                       (const unsigned short*)nullptr,
                       flags, hF, 1, 0);

    const int AB = NN / 8;              // 6250
    const int GB = (NN + 63) / 64;      // 782

    // layer 1: agg(hF) -> d_out scratch; h1F = relu(hF@Ws1 + agg@Wn1 + b1)
    hipLaunchKernelGGL(gs_agg, dim3(AB), dim3(256), 0, stream, hF, row_start, eidx,
                       (float*)d_out);
    hipLaunchKernelGGL(gs_mm, dim3(GB), dim3(256), 0, stream,
                       (const void*)hF, 128, wt_hs1, wt_ls1, 128, b1,
                       (const void*)nullptr, 0, (const unsigned short*)nullptr,
                       (const unsigned short*)nullptr, 0, (const void*)nullptr,
                       GB, NN, 0,
                       (const float*)d_out, wt_hn1, wt_ln1,
                       flags, h1F, 0, 1);

    // layer 2: agg(h1F) -> hF scratch; d_out = h1F@Ws2 + agg@Wn2 + b2 (f32)
    hipLaunchKernelGGL(gs_agg, dim3(AB), dim3(256), 0, stream, h1F, row_start, eidx, hF);
    hipLaunchKernelGGL(gs_mm, dim3(GB), dim3(256), 0, stream,
                       (const void*)h1F, 128, wt_hs2, wt_ls2, 128, b2v,
                       (const void*)nullptr, 0, (const unsigned short*)nullptr,
                       (const unsigned short*)nullptr, 0, (const void*)nullptr,
                       GB, NN, 0,
                       (const float*)hF, wt_hn2, wt_ln2,
                       flags, (float*)d_out, 0, 0);
}

// Round 7
// 447.173 us; speedup vs baseline: 1.0569x; 1.0569x over previous
//
#include <hip/hip_runtime.h>

#define N_DIS 25000
#define N_MIR 25000
#define NN    50000
#define E_NUM 600000
#define EMB   128

typedef __attribute__((ext_vector_type(8))) short short8v;   // 8 bf16 payloads (4 VGPR)
typedef __attribute__((ext_vector_type(4))) float floatx4;   // MFMA acc (4 VGPR)

typedef const unsigned int __attribute__((address_space(1))) as1_u32;
typedef unsigned int __attribute__((address_space(3))) as3_u32;

// async global->LDS, 16B per lane, linear LDS dest (wave-uniform base + lane*16).
__device__ __forceinline__ void gld16(const void* g, void* lds) {
    __builtin_amdgcn_global_load_lds((as1_u32*)g, (as3_u32*)lds, 16, 0, 0);
}

// v_mfma_f32_16x16x32_bf16 via inline asm: robust to builtin vector-elt-type conventions.
__device__ __forceinline__ floatx4 mfma_bf16_16x16x32(short8v a, short8v b, floatx4 c) {
    asm("v_mfma_f32_16x16x32_bf16 %0, %1, %2, %0" : "+v"(c) : "v"(a), "v"(b));
    return c;
}

// bf16 <-> f32 via bit ops (no hip_bf16.h; no bf16 types in any kernel signature)
__device__ __forceinline__ float us2f(unsigned short u) {
    return __uint_as_float(((unsigned)u) << 16);
}
__device__ __forceinline__ unsigned short f2us(float f) {
    unsigned u = __float_as_uint(f);
    unsigned r = ((u >> 16) & 1u) + 0x7FFFu;  // round-to-nearest-even
    u += r;
    return (unsigned short)(u >> 16);
}
__device__ __forceinline__ float loadf(const void* p, size_t i, bool isbf) {
    if (isbf) return us2f(((const unsigned short*)p)[i]);
    return ((const float*)p)[i];
}

// ---------------- init: zero counts + flag ----------------
__global__ __launch_bounds__(256) void gs_zero(int* counts, int* flags) {
    int i = blockIdx.x * blockDim.x + threadIdx.x;
    if (i < NN) counts[i] = 0;
    if (i < 8) flags[i] = 0;
}

__global__ __launch_bounds__(64) void gs_setflag(int* flags, int v) {
    if (threadIdx.x == 0) flags[0] = v;
}

// dtype probe: bf16 data -> low-16 exponent near 127 (plausible w.p. ~0.99);
// f32 data -> low 16 bits are mantissa junk (plausible w.p. ~0.07). flags[0] += count.
__global__ __launch_bounds__(256) void gs_probe(const void* x, int* flags) {
    const unsigned* u = (const unsigned*)x;
    unsigned w = u[threadIdx.x];
    int e = (int)((w >> 7) & 0xFF);
    if (e >= 118 && e <= 135) atomicAdd(&flags[0], 1);
}

// ---------------- weight prep: WT[c][k] = split-bf16 of W[k][c], zero-padded to Kp ------
__global__ __launch_bounds__(256) void gs_prepw(const void* Wd, const void* Wm,
                                                const void* Ws1, const void* Wn1,
                                                const void* Ws2, const void* Wn2,
                                                const int* flags, unsigned short* wt) {
    const bool isbf = flags[0] > 128;
    const int t = threadIdx.x;
    const int w = blockIdx.x >> 2;
    const int cq = (blockIdx.x & 3) * 32;
    const void* W;
    unsigned short* oh;
    unsigned short* ol;
    int K, Kp;
    if (w == 0)      { W = Wd;  oh = wt + 0;      ol = wt + 49152;  K = 383; Kp = 384; }
    else if (w == 1) { W = Wm;  oh = wt + 98304;  ol = wt + 163840; K = 495; Kp = 512; }
    else if (w == 2) { W = Ws1; oh = wt + 229376; ol = wt + 245760; K = 128; Kp = 128; }
    else if (w == 3) { W = Wn1; oh = wt + 262144; ol = wt + 278528; K = 128; Kp = 128; }
    else if (w == 4) { W = Ws2; oh = wt + 294912; ol = wt + 311296; K = 128; Kp = 128; }
    else             { W = Wn2; oh = wt + 327680; ol = wt + 344064; K = 128; Kp = 128; }
    for (int c = cq; c < cq + 32; ++c) {
        for (int k = t; k < Kp; k += 256) {
            float x = (k < K) ? loadf(W, (size_t)k * EMB + c, isbf) : 0.f;
            unsigned short h = f2us(x);
            oh[(size_t)c * Kp + k] = h;
            ol[(size_t)c * Kp + k] = f2us(x - us2f(h));
        }
    }
}

// ---------------- CSR build ----------------
__global__ __launch_bounds__(256) void gs_count(const int* dst, int* counts) {
    int e = blockIdx.x * blockDim.x + threadIdx.x;
    if (e < E_NUM) {
        unsigned d = (unsigned)dst[e];
        if (d < (unsigned)NN) atomicAdd(&counts[d], 1);
    }
}

__global__ __launch_bounds__(256) void gs_scan1(const int* counts, int* row_start, int* bsums) {
    __shared__ int tsum[256];
    const int t = threadIdx.x;
    const int base = blockIdx.x * 1024 + t * 4;
    int v0 = (base + 0 < NN) ? counts[base + 0] : 0;
    int v1 = (base + 1 < NN) ? counts[base + 1] : 0;
    int v2 = (base + 2 < NN) ? counts[base + 2] : 0;
    int v3 = (base + 3 < NN) ? counts[base + 3] : 0;
    int s = v0 + v1 + v2 + v3;
    tsum[t] = s;
    __syncthreads();
    for (int off = 1; off < 256; off <<= 1) {
        int xv = 0;
        if (t >= off) xv = tsum[t - off];
        __syncthreads();
        tsum[t] += xv;
        __syncthreads();
    }
    int excl = tsum[t] - s;
    if (base + 0 < NN) row_start[base + 0] = excl;
    excl += v0;
    if (base + 1 < NN) row_start[base + 1] = excl;
    excl += v1;
    if (base + 2 < NN) row_start[base + 2] = excl;
    excl += v2;
    if (base + 3 < NN) row_start[base + 3] = excl;
    if (t == 255) bsums[blockIdx.x] = tsum[255];
}

__global__ __launch_bounds__(64) void gs_scan2(int* bsums, int* row_start, int nb) {
    if (threadIdx.x == 0) {
        int run = 0;
        for (int i = 0; i < nb; ++i) {
            int v = bsums[i];
            bsums[i] = run;
            run += v;
        }
        row_start[NN] = run;
    }
}

__global__ __launch_bounds__(256) void gs_scan3(int* row_start, int* cursor, const int* bsums) {
    const int t = threadIdx.x;
    const int base = blockIdx.x * 1024 + t * 4;
    const int add = bsums[blockIdx.x];
    for (int i = 0; i < 4; ++i) {
        int idx = base + i;
        if (idx < NN) {
            int v = row_start[idx] + add;
            row_start[idx] = v;
            cursor[idx] = v;
        }
    }
}

__global__ __launch_bounds__(256) void gs_scatter(const int* src, const int* dst, int* cursor,
                                                  int* eidx) {
    int e = blockIdx.x * blockDim.x + threadIdx.x;
    if (e < E_NUM) {
        unsigned d = (unsigned)dst[e];
        unsigned sv = (unsigned)src[e];
        if (d < (unsigned)NN && sv < (unsigned)NN) {
            int p = atomicAdd(&cursor[d], 1);
            eidx[p] = (int)sv;
        }
    }
}

// ---------------- mean aggregation: agg[n] = mean_{e in CSR[n]} x[eidx[e]] ----------------
__global__ __launch_bounds__(256) void gs_agg(const float* __restrict__ x,
                                              const int* __restrict__ row_start,
                                              const int* __restrict__ eidx,
                                              float* __restrict__ agg) {
    const int t = threadIdx.x;
    const int row = blockIdx.x * 8 + (t >> 5);
    const int tc = (t & 31) * 4;
    if (row >= NN) return;
    const int s0 = row_start[row];
    const int s1 = row_start[row + 1];
    float a0x = 0.f, a0y = 0.f, a0z = 0.f, a0w = 0.f;
    float a1x = 0.f, a1y = 0.f, a1z = 0.f, a1w = 0.f;
    int e = s0;
    for (; e + 1 < s1; e += 2) {
        int sa = eidx[e];
        int sb = eidx[e + 1];
        float4 va = *(const float4*)&x[(size_t)sa * EMB + tc];
        float4 vb = *(const float4*)&x[(size_t)sb * EMB + tc];
        a0x += va.x; a0y += va.y; a0z += va.z; a0w += va.w;
        a1x += vb.x; a1y += vb.y; a1z += vb.z; a1w += vb.w;
    }
    if (e < s1) {
        int sa = eidx[e];
        float4 va = *(const float4*)&x[(size_t)sa * EMB + tc];
        a0x += va.x; a0y += va.y; a0z += va.z; a0w += va.w;
    }
    float inv = (s1 > s0) ? 1.f / (float)(s1 - s0) : 0.f;
    float4 o;
    o.x = (a0x + a1x) * inv;
    o.y = (a0y + a1y) * inv;
    o.z = (a0z + a1z) * inv;
    o.w = (a0w + a1w) * inv;
    *(float4*)&agg[(size_t)row * EMB + tc] = o;
}

// ---------------- MFMA GEMM, W panels staged via global_load_lds ----------------
// BM=64 rows/block, 256 threads = 4 waves in 2x2 (each wave: 32 rows x 64 cols).
// KC=64 per chunk. LDS 48KB single-buffer (3 blocks/CU).
// W staging: global_load_lds width=16, LINEAR LDS dest, PRE-SWIZZLED per-lane global src
// (src granule = g16 ^ ((col&7)<<4), an involution) -> LDS content identical to the proven
// round-5 swizzled layout; no destination VGPRs -> no register-starved serialization.
// X staging: reg load + trunc-split f32->bf16 hi/lo + swizzled ds_write (unchanged).
// Split math: x = xh + xl, w = wh + wl; D += xh*wh + xl*wh + xh*wl.
__global__ __launch_bounds__(256, 3) void gs_mm(
    const void* __restrict__ Xa, int Ka, const unsigned short* __restrict__ WAh,
    const unsigned short* __restrict__ WAl, int KpA, const void* __restrict__ ba,
    const void* __restrict__ Xb, int Kb, const unsigned short* __restrict__ WBh,
    const unsigned short* __restrict__ WBl, int KpB, const void* __restrict__ bb,
    int splitB, int Ma, int Mb,
    const float* __restrict__ X2, const unsigned short* __restrict__ W2h,
    const unsigned short* __restrict__ W2l,
    const int* __restrict__ flags, float* __restrict__ out, int x1_dyn, int do_relu) {
    __shared__ __align__(16) unsigned char sm[49152];
    unsigned char* smXH = sm;           //  8 KB: Xh [64 rows][128 B]
    unsigned char* smXL = sm + 8192;    //  8 KB: Xl
    unsigned char* smWH = sm + 16384;   // 16 KB: Wh [128 cols][128 B]
    unsigned char* smWL = sm + 32768;   // 16 KB: Wl
    const bool isbf = flags[0] > 128;
    const int t = threadIdx.x;
    const bool sideB = (int)blockIdx.x >= splitB;
    const void* X1 = sideB ? Xb : Xa;
    const unsigned short* W1h = sideB ? WBh : WAh;
    const unsigned short* W1l = sideB ? WBl : WAl;
    const int K1 = sideB ? Kb : Ka;
    const int Kp1 = sideB ? KpB : KpA;
    const void* bias = sideB ? bb : ba;
    const int M = sideB ? Mb : Ma;
    const int r0 = (sideB ? ((int)blockIdx.x - splitB) : (int)blockIdx.x) * 64;
    float* outb = out + (sideB ? (size_t)Ma * EMB : 0);
    const bool x1bf = (x1_dyn != 0) && isbf;

    const int l = t & 63;
    const int wv = t >> 6;
    const int wr = wv >> 1, wc = wv & 1;  // 2x2 wave grid
    const int lr = l & 15, lg = l >> 4;   // fragment lane decomposition

    floatx4 acc[2][4];
#pragma unroll
    for (int rt = 0; rt < 2; ++rt)
#pragma unroll
        for (int ct = 0; ct < 4; ++ct) acc[rt][ct] = (floatx4){0.f, 0.f, 0.f, 0.f};

    const int nch1 = (K1 + 63) >> 6;
    const int totch = nch1 + (X2 ? 2 : 0);

    // X staging thread mapping
    const int srX = t >> 2;          // row 0..63
    const int skX = (t & 3) << 4;    // k base (16 k per thread)

    for (int ch = 0; ch < totch; ++ch) {
        const void* cX;
        const unsigned short* cWh;
        const unsigned short* cWl;
        int ck0, cK, cKp;
        bool cxbf;
        if (ch < nch1) {
            cX = X1; cWh = W1h; cWl = W1l; ck0 = ch << 6; cK = K1; cKp = Kp1; cxbf = x1bf;
        } else {
            cX = (const void*)X2; cWh = W2h; cWl = W2l;
            ck0 = (ch - nch1) << 6; cK = 128; cKp = 128; cxbf = false;
        }
        const bool cvec = (!cxbf) && (cK == 128);

        __syncthreads();  // previous chunk's compute fully consumed LDS

        // ---- W stage: global_load_lds, pre-swizzled global src, linear LDS dest ----
        // Each wave covers 4 KB of each 16 KB plane: 4 instrs x 64 lanes x 16 B.
#pragma unroll
        for (int i = 0; i < 4; ++i) {
            const int p = (wv << 12) + (i << 10) + (l << 4);  // LDS byte this lane fills
            const int col = p >> 7;
            const int g16 = p & 0x7F;
            const size_t so = ((size_t)col * cKp + ck0) * 2 + (size_t)(g16 ^ ((col & 7) << 4));
            gld16((const unsigned char*)cWh + so, smWH + (wv << 12) + (i << 10));
            if (!isbf) gld16((const unsigned char*)cWl + so, smWL + (wv << 12) + (i << 10));
        }

        // ---- X stage: load + trunc-split + swizzled ds_write ----
        {
            const int gr = r0 + srX;
            unsigned xu[16];
            if (cvec) {
                if (gr < M) {
                    const float* p = &((const float*)cX)[(size_t)gr * 128 + ck0 + skX];
#pragma unroll
                    for (int q = 0; q < 4; ++q) {
                        float4 v = *(const float4*)(p + (q << 2));
                        xu[q * 4 + 0] = __float_as_uint(v.x);
                        xu[q * 4 + 1] = __float_as_uint(v.y);
                        xu[q * 4 + 2] = __float_as_uint(v.z);
                        xu[q * 4 + 3] = __float_as_uint(v.w);
                    }
                } else {
#pragma unroll
                    for (int j = 0; j < 16; ++j) xu[j] = 0u;
                }
            } else {
#pragma unroll
                for (int j = 0; j < 16; ++j) {
                    int gk = ck0 + skX + j;
                    unsigned v = 0u;
                    if (gr < M && gk < cK)
                        v = cxbf ? (unsigned)((const unsigned short*)cX)[(size_t)gr * cK + gk]
                                 : ((const unsigned*)cX)[(size_t)gr * cK + gk];
                    xu[j] = v;
                }
            }
            const int rowoff = srX << 7;
            const int swz = (srX & 7) << 4;
#pragma unroll
            for (int g = 0; g < 2; ++g) {
                short8v vh, vl;
#pragma unroll
                for (int e = 0; e < 8; ++e) {
                    unsigned u = xu[(g << 3) + e];
                    if (cxbf) {
                        vh[e] = (short)u;
                        vl[e] = 0;
                    } else {
                        unsigned short h = (unsigned short)(u >> 16);
                        vh[e] = (short)h;
                        vl[e] = (short)f2us(__uint_as_float(u) - us2f(h));
                    }
                }
                const int off = rowoff + ((((skX << 1) + (g << 4))) ^ swz);
                *(short8v*)(smXH + off) = vh;
                if (!cxbf) *(short8v*)(smXL + off) = vl;
            }
        }
        __syncthreads();  // drains vmcnt(0) (gload_lds) + lgkmcnt(0) (ds_writes)

        // ---- compute: 2 k-steps x (2 row-tiles x 4 col-tiles), split MFMA ----
        const bool skip_xl = cxbf;   // X was bf16 -> Xl == 0
        const bool skip_wl = isbf;   // W was bf16 -> Wl == 0
#pragma unroll
        for (int ks = 0; ks < 2; ++ks) {
            const int kbyte = (ks << 6) + (lg << 4);
            short8v ah[2], al[2];
#pragma unroll
            for (int rt = 0; rt < 2; ++rt) {
                const int row = wr * 32 + rt * 16 + lr;
                const int off = (row << 7) + (kbyte ^ ((row & 7) << 4));
                ah[rt] = *(const short8v*)(smXH + off);
                if (!skip_xl) al[rt] = *(const short8v*)(smXL + off);
            }
#pragma unroll
            for (int ct = 0; ct < 4; ++ct) {
                const int col = wc * 64 + ct * 16 + lr;
                const int boff = (col << 7) + (kbyte ^ ((col & 7) << 4));
                short8v bh = *(const short8v*)(smWH + boff);
                acc[0][ct] = mfma_bf16_16x16x32(ah[0], bh, acc[0][ct]);
                acc[1][ct] = mfma_bf16_16x16x32(ah[1], bh, acc[1][ct]);
                if (!skip_xl) {
                    acc[0][ct] = mfma_bf16_16x16x32(al[0], bh, acc[0][ct]);
                    acc[1][ct] = mfma_bf16_16x16x32(al[1], bh, acc[1][ct]);
                }
                if (!skip_wl) {
                    short8v bl = *(const short8v*)(smWL + boff);
                    acc[0][ct] = mfma_bf16_16x16x32(ah[0], bl, acc[0][ct]);
                    acc[1][ct] = mfma_bf16_16x16x32(ah[1], bl, acc[1][ct]);
                }
            }
        }
    }

    // ---- epilogue: D[i][j] lane map (m89): j = lane&15, i = 4*(lane>>4)+reg ----
#pragma unroll
    for (int ct = 0; ct < 4; ++ct) {
        const int col = wc * 64 + ct * 16 + lr;
        const float bbv = loadf(bias, col, isbf);
#pragma unroll
        for (int rt = 0; rt < 2; ++rt) {
#pragma unroll
            for (int rr = 0; rr < 4; ++rr) {
                const int row = r0 + wr * 32 + rt * 16 + (lg << 2) + rr;
                if (row < M) {
                    float v = acc[rt][ct][rr] + bbv;
                    if (do_relu) v = v > 0.f ? v : 0.f;
                    outb[(size_t)row * EMB + col] = v;
                }
            }
        }
    }
}

extern "C" __attribute__((visibility("default"))) void kernel_launch(
    void* const* d_in, const int* in_sizes, int n_in, void* d_out, int out_size, void* d_ws,
    size_t ws_size, hipStream_t stream) {
    // ---- ordering + dtype from in_sizes[0] (d_features in dict order, W_d if sorted) ----
    int iDF = 0, iMF = 1, iSRC = 2, iDST = 3, iWD = 4, iBD = 5, iWM = 6, iBM = 7;
    int iWS1 = 8, iWN1 = 9, iB1 = 10, iWS2 = 11, iWN2 = 12, iB2 = 13;
    long u0 = in_sizes ? (long)in_sizes[0] : 9575000L;
    int dt = -1;  // -1 unknown (probe), 0 f32, 1 bf16
    if (u0 == 49024L || u0 == 98048L || u0 == 196096L) {
        iWD = 0; iWM = 1; iWN1 = 2; iWN2 = 3; iWS1 = 4; iWS2 = 5;
        iB1 = 6; iB2 = 7; iBD = 8; iBM = 9; iDF = 10; iDST = 11; iMF = 12; iSRC = 13;
        if (u0 == 98048L) dt = 1;
        else if (u0 == 196096L) dt = 0;
    } else {
        if (u0 == 19150000L) dt = 1;       // bytes, bf16
        else if (u0 == 38300000L) dt = 0;  // bytes, f32
    }
    const void* d_features = d_in[iDF];
    const void* m_features = d_in[iMF];
    const int* src = (const int*)d_in[iSRC];
    const int* dst = (const int*)d_in[iDST];
    const void* W_d = d_in[iWD];
    const void* b_d = d_in[iBD];
    const void* W_m = d_in[iWM];
    const void* b_m = d_in[iBM];
    const void* W_self1 = d_in[iWS1];
    const void* W_neigh1 = d_in[iWN1];
    const void* b1 = d_in[iB1];
    const void* W_self2 = d_in[iWS2];
    const void* W_neigh2 = d_in[iWN2];
    const void* b2v = d_in[iB2];

    // ---- workspace layout (~54.92 MB) ----
    char* w = (char*)d_ws;
    int* flags = (int*)(w + 0);            //        64 B
    int* counts = (int*)(w + 64);          //   200,000 B
    int* row_start = (int*)(w + 200064);   //   200,004 B (pad to 400128)
    int* cursor = (int*)(w + 400128);      //   200,000 B
    int* bsums = (int*)(w + 600128);       //       256 B
    int* eidx = (int*)(w + 600384);        // 2,400,000 B (pad to 3000448)
    unsigned short* wt = (unsigned short*)(w + 3000448);  // 720,896 B of split-bf16 WT panels
    unsigned short* wt_hd = wt + 0;
    unsigned short* wt_ld = wt + 49152;
    unsigned short* wt_hm = wt + 98304;
    unsigned short* wt_lm = wt + 163840;
    unsigned short* wt_hs1 = wt + 229376;
    unsigned short* wt_ls1 = wt + 245760;
    unsigned short* wt_hn1 = wt + 262144;
    unsigned short* wt_ln1 = wt + 278528;
    unsigned short* wt_hs2 = wt + 294912;
    unsigned short* wt_ls2 = wt + 311296;
    unsigned short* wt_hn2 = wt + 327680;
    unsigned short* wt_ln2 = wt + 344064;
    float* hF = (float*)(w + 3721344);     // 25,600,000 B
    float* h1F = (float*)(w + 29321344);   // 25,600,000 B -> ends 54,921,344
    // agg scratch: layer1 agg -> d_out (overwritten later); layer2 agg -> hF (dead after L1)

    const int NB_SCAN = (NN + 1023) / 1024;  // 49
    const int EB = (E_NUM + 255) / 256;      // 2344
    const int ZB = (NN + 255) / 256;         // 196

    // init + dtype resolution (flags[0] > 128 => bf16)
    hipLaunchKernelGGL(gs_zero, dim3(ZB), dim3(256), 0, stream, counts, flags);
    if (dt == 1)
        hipLaunchKernelGGL(gs_setflag, dim3(1), dim3(64), 0, stream, flags, 1000);
    else if (dt == 0)
        hipLaunchKernelGGL(gs_setflag, dim3(1), dim3(64), 0, stream, flags, 0);
    else
        hipLaunchKernelGGL(gs_probe, dim3(1), dim3(256), 0, stream, d_features, flags);

    // weight prep (after dtype resolution)
    hipLaunchKernelGGL(gs_prepw, dim3(24), dim3(256), 0, stream, W_d, W_m, W_self1, W_neigh1,
                       W_self2, W_neigh2, flags, wt);

    // CSR build
    hipLaunchKernelGGL(gs_count, dim3(EB), dim3(256), 0, stream, dst, counts);
    hipLaunchKernelGGL(gs_scan1, dim3(NB_SCAN), dim3(256), 0, stream, counts, row_start, bsums);
    hipLaunchKernelGGL(gs_scan2, dim3(1), dim3(64), 0, stream, bsums, row_start, NB_SCAN);
    hipLaunchKernelGGL(gs_scan3, dim3(NB_SCAN), dim3(256), 0, stream, row_start, cursor, bsums);
    hipLaunchKernelGGL(gs_scatter, dim3(EB), dim3(256), 0, stream, src, dst, cursor, eidx);

    // both projections in ONE dispatch (block-split): blocks [0,391) disease, [391,782) mirna
    const int PBd = (N_DIS + 63) / 64;  // 391
    hipLaunchKernelGGL(gs_mm, dim3(2 * PBd), dim3(256), 0, stream,
                       d_features, 383, wt_hd, wt_ld, 384, b_d,
                       m_features, 495, wt_hm, wt_lm, 512, b_m,
                       PBd, N_DIS, N_MIR,
                       (const float*)nullptr, (const unsigned short*)nullptr,
                       (const unsigned short*)nullptr,
                       flags, hF, 1, 0);

    const int AB = NN / 8;              // 6250
    const int GB = (NN + 63) / 64;      // 782

    // layer 1: agg(hF) -> d_out scratch; h1F = relu(hF@Ws1 + agg@Wn1 + b1)
    hipLaunchKernelGGL(gs_agg, dim3(AB), dim3(256), 0, stream, hF, row_start, eidx,
                       (float*)d_out);
    hipLaunchKernelGGL(gs_mm, dim3(GB), dim3(256), 0, stream,
                       (const void*)hF, 128, wt_hs1, wt_ls1, 128, b1,
                       (const void*)nullptr, 0, (const unsigned short*)nullptr,
                       (const unsigned short*)nullptr, 0, (const void*)nullptr,
                       GB, NN, 0,
                       (const float*)d_out, wt_hn1, wt_ln1,
                       flags, h1F, 0, 1);

    // layer 2: agg(h1F) -> hF scratch; d_out = h1F@Ws2 + agg@Wn2 + b2 (f32)
    hipLaunchKernelGGL(gs_agg, dim3(AB), dim3(256), 0, stream, h1F, row_start, eidx, hF);
    hipLaunchKernelGGL(gs_mm, dim3(GB), dim3(256), 0, stream,
                       (const void*)h1F, 128, wt_hs2, wt_ls2, 128, b2v,
                       (const void*)nullptr, 0, (const unsigned short*)nullptr,
                       (const unsigned short*)nullptr, 0, (const void*)nullptr,
                       GB, NN, 0,
                       (const float*)hF, wt_hn2, wt_ln2,
                       flags, (float*)d_out, 0, 0);
}

// Round 8
// 434.845 us; speedup vs baseline: 1.0869x; 1.0283x over previous
//
#include <hip/hip_runtime.h>

#define N_DIS 25000
#define N_MIR 25000
#define NN    50000
#define E_NUM 600000
#define EMB   128

typedef __attribute__((ext_vector_type(8))) short short8v;   // 8 bf16 payloads (4 VGPR)
typedef __attribute__((ext_vector_type(4))) float floatx4;   // MFMA acc (4 VGPR)

typedef const unsigned int __attribute__((address_space(1))) as1_u32;
typedef unsigned int __attribute__((address_space(3))) as3_u32;

// async global->LDS, 16B per lane, linear LDS dest (wave-uniform base + lane*16).
__device__ __forceinline__ void gld16(const void* g, void* lds) {
    __builtin_amdgcn_global_load_lds((as1_u32*)g, (as3_u32*)lds, 16, 0, 0);
}

// v_mfma_f32_16x16x32_bf16 via inline asm.
__device__ __forceinline__ floatx4 mfma_bf16_16x16x32(short8v a, short8v b, floatx4 c) {
    asm("v_mfma_f32_16x16x32_bf16 %0, %1, %2, %0" : "+v"(c) : "v"(a), "v"(b));
    return c;
}

// bf16 <-> f32 via bit ops (no hip_bf16.h; no bf16 types in any kernel signature)
__device__ __forceinline__ float us2f(unsigned short u) {
    return __uint_as_float(((unsigned)u) << 16);
}
__device__ __forceinline__ unsigned short f2us(float f) {
    unsigned u = __float_as_uint(f);
    unsigned r = ((u >> 16) & 1u) + 0x7FFFu;  // round-to-nearest-even
    u += r;
    return (unsigned short)(u >> 16);
}
__device__ __forceinline__ float loadf(const void* p, size_t i, bool isbf) {
    if (isbf) return us2f(((const unsigned short*)p)[i]);
    return ((const float*)p)[i];
}

// ---------------- init: zero counts + flag ----------------
__global__ __launch_bounds__(256) void gs_zero(int* counts, int* flags) {
    int i = blockIdx.x * blockDim.x + threadIdx.x;
    if (i < NN) counts[i] = 0;
    if (i < 8) flags[i] = 0;
}

__global__ __launch_bounds__(64) void gs_setflag(int* flags, int v) {
    if (threadIdx.x == 0) flags[0] = v;
}

// dtype probe: bf16 data -> low-16 exponent near 127. flags[0] += count.
__global__ __launch_bounds__(256) void gs_probe(const void* x, int* flags) {
    const unsigned* u = (const unsigned*)x;
    unsigned w = u[threadIdx.x];
    int e = (int)((w >> 7) & 0xFF);
    if (e >= 118 && e <= 135) atomicAdd(&flags[0], 1);
}

// ---------------- weight prep: WT[c][k] = split-bf16 of W[k][c], zero-padded to Kp ------
__global__ __launch_bounds__(256) void gs_prepw(const void* Wd, const void* Wm,
                                                const void* Ws1, const void* Wn1,
                                                const void* Ws2, const void* Wn2,
                                                const int* flags, unsigned short* wt) {
    const bool isbf = flags[0] > 128;
    const int t = threadIdx.x;
    const int w = blockIdx.x >> 2;
    const int cq = (blockIdx.x & 3) * 32;
    const void* W;
    unsigned short* oh;
    unsigned short* ol;
    int K, Kp;
    if (w == 0)      { W = Wd;  oh = wt + 0;      ol = wt + 49152;  K = 383; Kp = 384; }
    else if (w == 1) { W = Wm;  oh = wt + 98304;  ol = wt + 163840; K = 495; Kp = 512; }
    else if (w == 2) { W = Ws1; oh = wt + 229376; ol = wt + 245760; K = 128; Kp = 128; }
    else if (w == 3) { W = Wn1; oh = wt + 262144; ol = wt + 278528; K = 128; Kp = 128; }
    else if (w == 4) { W = Ws2; oh = wt + 294912; ol = wt + 311296; K = 128; Kp = 128; }
    else             { W = Wn2; oh = wt + 327680; ol = wt + 344064; K = 128; Kp = 128; }
    for (int c = cq; c < cq + 32; ++c) {
        for (int k = t; k < Kp; k += 256) {
            float x = (k < K) ? loadf(W, (size_t)k * EMB + c, isbf) : 0.f;
            unsigned short h = f2us(x);
            oh[(size_t)c * Kp + k] = h;
            ol[(size_t)c * Kp + k] = f2us(x - us2f(h));
        }
    }
}

// ---------------- CSR build ----------------
__global__ __launch_bounds__(256) void gs_count(const int* dst, int* counts) {
    int e = blockIdx.x * blockDim.x + threadIdx.x;
    if (e < E_NUM) {
        unsigned d = (unsigned)dst[e];
        if (d < (unsigned)NN) atomicAdd(&counts[d], 1);
    }
}

__global__ __launch_bounds__(256) void gs_scan1(const int* counts, int* row_start, int* bsums) {
    __shared__ int tsum[256];
    const int t = threadIdx.x;
    const int base = blockIdx.x * 1024 + t * 4;
    int v0 = (base + 0 < NN) ? counts[base + 0] : 0;
    int v1 = (base + 1 < NN) ? counts[base + 1] : 0;
    int v2 = (base + 2 < NN) ? counts[base + 2] : 0;
    int v3 = (base + 3 < NN) ? counts[base + 3] : 0;
    int s = v0 + v1 + v2 + v3;
    tsum[t] = s;
    __syncthreads();
    for (int off = 1; off < 256; off <<= 1) {
        int xv = 0;
        if (t >= off) xv = tsum[t - off];
        __syncthreads();
        tsum[t] += xv;
        __syncthreads();
    }
    int excl = tsum[t] - s;
    if (base + 0 < NN) row_start[base + 0] = excl;
    excl += v0;
    if (base + 1 < NN) row_start[base + 1] = excl;
    excl += v1;
    if (base + 2 < NN) row_start[base + 2] = excl;
    excl += v2;
    if (base + 3 < NN) row_start[base + 3] = excl;
    if (t == 255) bsums[blockIdx.x] = tsum[255];
}

__global__ __launch_bounds__(64) void gs_scan2(int* bsums, int* row_start, int nb) {
    if (threadIdx.x == 0) {
        int run = 0;
        for (int i = 0; i < nb; ++i) {
            int v = bsums[i];
            bsums[i] = run;
            run += v;
        }
        row_start[NN] = run;
    }
}

__global__ __launch_bounds__(256) void gs_scan3(int* row_start, int* cursor, const int* bsums) {
    const int t = threadIdx.x;
    const int base = blockIdx.x * 1024 + t * 4;
    const int add = bsums[blockIdx.x];
    for (int i = 0; i < 4; ++i) {
        int idx = base + i;
        if (idx < NN) {
            int v = row_start[idx] + add;
            row_start[idx] = v;
            cursor[idx] = v;
        }
    }
}

__global__ __launch_bounds__(256) void gs_scatter(const int* src, const int* dst, int* cursor,
                                                  int* eidx) {
    int e = blockIdx.x * blockDim.x + threadIdx.x;
    if (e < E_NUM) {
        unsigned d = (unsigned)dst[e];
        unsigned sv = (unsigned)src[e];
        if (d < (unsigned)NN && sv < (unsigned)NN) {
            int p = atomicAdd(&cursor[d], 1);
            eidx[p] = (int)sv;
        }
    }
}

// ------- mean aggregation over split-bf16 planes: out planes = mean of (h+l) rows -------
__global__ __launch_bounds__(256) void gs_aggp(const unsigned short* __restrict__ xh,
                                               const unsigned short* __restrict__ xl,
                                               const int* __restrict__ row_start,
                                               const int* __restrict__ eidx,
                                               unsigned short* __restrict__ oh,
                                               unsigned short* __restrict__ ol) {
    const int t = threadIdx.x;
    const int row = blockIdx.x * 8 + (t >> 5);
    const int c4 = (t & 31) * 4;
    if (row >= NN) return;
    const int s0 = row_start[row];
    const int s1 = row_start[row + 1];
    float a0 = 0.f, a1 = 0.f, a2 = 0.f, a3 = 0.f;
    float b0 = 0.f, b1 = 0.f, b2 = 0.f, b3 = 0.f;
    int e = s0;
    for (; e + 1 < s1; e += 2) {
        int sa = eidx[e];
        int sb = eidx[e + 1];
        ushort4 ha = *(const ushort4*)&xh[(size_t)sa * EMB + c4];
        ushort4 la = *(const ushort4*)&xl[(size_t)sa * EMB + c4];
        ushort4 hb = *(const ushort4*)&xh[(size_t)sb * EMB + c4];
        ushort4 lb = *(const ushort4*)&xl[(size_t)sb * EMB + c4];
        a0 += us2f(ha.x) + us2f(la.x); a1 += us2f(ha.y) + us2f(la.y);
        a2 += us2f(ha.z) + us2f(la.z); a3 += us2f(ha.w) + us2f(la.w);
        b0 += us2f(hb.x) + us2f(lb.x); b1 += us2f(hb.y) + us2f(lb.y);
        b2 += us2f(hb.z) + us2f(lb.z); b3 += us2f(hb.w) + us2f(lb.w);
    }
    if (e < s1) {
        int sa = eidx[e];
        ushort4 ha = *(const ushort4*)&xh[(size_t)sa * EMB + c4];
        ushort4 la = *(const ushort4*)&xl[(size_t)sa * EMB + c4];
        a0 += us2f(ha.x) + us2f(la.x); a1 += us2f(ha.y) + us2f(la.y);
        a2 += us2f(ha.z) + us2f(la.z); a3 += us2f(ha.w) + us2f(la.w);
    }
    float inv = (s1 > s0) ? 1.f / (float)(s1 - s0) : 0.f;
    float f0 = (a0 + b0) * inv, f1 = (a1 + b1) * inv;
    float f2 = (a2 + b2) * inv, f3 = (a3 + b3) * inv;
    ushort4 vh, vl;
    unsigned short h;
    h = f2us(f0); vh.x = h; vl.x = f2us(f0 - us2f(h));
    h = f2us(f1); vh.y = h; vl.y = f2us(f1 - us2f(h));
    h = f2us(f2); vh.z = h; vl.z = f2us(f2 - us2f(h));
    h = f2us(f3); vh.w = h; vl.w = f2us(f3 - us2f(h));
    *(ushort4*)&oh[(size_t)row * EMB + c4] = vh;
    *(ushort4*)&ol[(size_t)row * EMB + c4] = vl;
}

// ---------------- proj MFMA GEMM (features @ W), output -> split bf16 planes -------------
// BM=64, 256 threads, 4 waves 2x2, KC=64, LDS 48KB. W via gload_lds (pre-swizzled src);
// X in-reg load + trunc-split + swizzled ds_write (K=383/495 paths).
__global__ __launch_bounds__(256, 3) void gs_mmp(
    const void* __restrict__ Xa, int Ka, const unsigned short* __restrict__ WAh,
    const unsigned short* __restrict__ WAl, int KpA, const void* __restrict__ ba,
    const void* __restrict__ Xb, int Kb, const unsigned short* __restrict__ WBh,
    const unsigned short* __restrict__ WBl, int KpB, const void* __restrict__ bb,
    int splitB, int Ma, int Mb,
    const int* __restrict__ flags, unsigned short* __restrict__ outH,
    unsigned short* __restrict__ outL) {
    __shared__ __align__(16) unsigned char sm[49152];
    unsigned char* smXH = sm;           //  8 KB
    unsigned char* smXL = sm + 8192;    //  8 KB
    unsigned char* smWH = sm + 16384;   // 16 KB
    unsigned char* smWL = sm + 32768;   // 16 KB
    const bool isbf = flags[0] > 128;
    const int t = threadIdx.x;
    const bool sideB = (int)blockIdx.x >= splitB;
    const void* X1 = sideB ? Xb : Xa;
    const unsigned short* W1h = sideB ? WBh : WAh;
    const unsigned short* W1l = sideB ? WBl : WAl;
    const int K1 = sideB ? Kb : Ka;
    const int Kp1 = sideB ? KpB : KpA;
    const void* bias = sideB ? bb : ba;
    const int M = sideB ? Mb : Ma;
    const int r0 = (sideB ? ((int)blockIdx.x - splitB) : (int)blockIdx.x) * 64;
    unsigned short* oh = outH + (sideB ? (size_t)Ma * EMB : 0);
    unsigned short* ol = outL + (sideB ? (size_t)Ma * EMB : 0);

    const int l = t & 63;
    const int wv = t >> 6;
    const int wr = wv >> 1, wc = wv & 1;
    const int lr = l & 15, lg = l >> 4;

    floatx4 acc[2][4];
#pragma unroll
    for (int rt = 0; rt < 2; ++rt)
#pragma unroll
        for (int ct = 0; ct < 4; ++ct) acc[rt][ct] = (floatx4){0.f, 0.f, 0.f, 0.f};

    const int nch1 = (K1 + 63) >> 6;
    const int srX = t >> 2;
    const int skX = (t & 3) << 4;
    const bool xbf = isbf;  // features share input dtype

    for (int ch = 0; ch < nch1; ++ch) {
        const int ck0 = ch << 6;
        __syncthreads();
        // W stage: gload_lds, pre-swizzled source, linear dest
#pragma unroll
        for (int i = 0; i < 4; ++i) {
            const int p = (wv << 12) + (i << 10) + (l << 4);
            const int col = p >> 7;
            const int g16 = p & 0x7F;
            const size_t so = ((size_t)col * Kp1 + ck0) * 2 + (size_t)(g16 ^ ((col & 7) << 4));
            gld16((const unsigned char*)W1h + so, smWH + (wv << 12) + (i << 10));
            if (!isbf) gld16((const unsigned char*)W1l + so, smWL + (wv << 12) + (i << 10));
        }
        // X stage: reg load + trunc-split + swizzled ds_write
        {
            const int gr = r0 + srX;
            unsigned xu[16];
#pragma unroll
            for (int j = 0; j < 16; ++j) {
                int gk = ck0 + skX + j;
                unsigned v = 0u;
                if (gr < M && gk < K1)
                    v = xbf ? (unsigned)((const unsigned short*)X1)[(size_t)gr * K1 + gk]
                            : ((const unsigned*)X1)[(size_t)gr * K1 + gk];
                xu[j] = v;
            }
            const int rowoff = srX << 7;
            const int swz = (srX & 7) << 4;
#pragma unroll
            for (int g = 0; g < 2; ++g) {
                short8v vh, vl;
#pragma unroll
                for (int e = 0; e < 8; ++e) {
                    unsigned u = xu[(g << 3) + e];
                    if (xbf) {
                        vh[e] = (short)u;
                        vl[e] = 0;
                    } else {
                        unsigned short h = (unsigned short)(u >> 16);
                        vh[e] = (short)h;
                        vl[e] = (short)f2us(__uint_as_float(u) - us2f(h));
                    }
                }
                const int off = rowoff + ((((skX << 1) + (g << 4))) ^ swz);
                *(short8v*)(smXH + off) = vh;
                if (!xbf) *(short8v*)(smXL + off) = vl;
            }
        }
        __syncthreads();
        // compute
#pragma unroll
        for (int ks = 0; ks < 2; ++ks) {
            const int kbyte = (ks << 6) + (lg << 4);
            short8v ah[2], al[2];
#pragma unroll
            for (int rt = 0; rt < 2; ++rt) {
                const int row = wr * 32 + rt * 16 + lr;
                const int off = (row << 7) + (kbyte ^ ((row & 7) << 4));
                ah[rt] = *(const short8v*)(smXH + off);
                if (!xbf) al[rt] = *(const short8v*)(smXL + off);
            }
#pragma unroll
            for (int ct = 0; ct < 4; ++ct) {
                const int col = wc * 64 + ct * 16 + lr;
                const int boff = (col << 7) + (kbyte ^ ((col & 7) << 4));
                short8v bh = *(const short8v*)(smWH + boff);
                acc[0][ct] = mfma_bf16_16x16x32(ah[0], bh, acc[0][ct]);
                acc[1][ct] = mfma_bf16_16x16x32(ah[1], bh, acc[1][ct]);
                if (!xbf) {
                    acc[0][ct] = mfma_bf16_16x16x32(al[0], bh, acc[0][ct]);
                    acc[1][ct] = mfma_bf16_16x16x32(al[1], bh, acc[1][ct]);
                }
                if (!isbf) {
                    short8v bl = *(const short8v*)(smWL + boff);
                    acc[0][ct] = mfma_bf16_16x16x32(ah[0], bl, acc[0][ct]);
                    acc[1][ct] = mfma_bf16_16x16x32(ah[1], bl, acc[1][ct]);
                }
            }
        }
    }

    // epilogue: write hF as split planes
#pragma unroll
    for (int ct = 0; ct < 4; ++ct) {
        const int col = wc * 64 + ct * 16 + lr;
        const float bbv = loadf(bias, col, isbf);
#pragma unroll
        for (int rt = 0; rt < 2; ++rt) {
#pragma unroll
            for (int rr = 0; rr < 4; ++rr) {
                const int row = r0 + wr * 32 + rt * 16 + (lg << 2) + rr;
                if (row < M) {
                    float v = acc[rt][ct][rr] + bbv;
                    unsigned short h = f2us(v);
                    oh[(size_t)row * EMB + col] = h;
                    ol[(size_t)row * EMB + col] = f2us(v - us2f(h));
                }
            }
        }
    }
}

// ---------------- layer MFMA GEMM: pure global_load_lds staging (all operands planes) ----
// BM=128, 512 threads = 8 waves (4r x 2c; wave = 32 rows x 64 cols). K = 128(X1) + 128(X2),
// 4 chunks of KC=64. LDS 64KB: XH/XL [128][128B], WH/WL [128][128B], all swizzle-content via
// pre-swizzled global source (involution within each 128B tile row). 2 blocks/CU.
__global__ __launch_bounds__(512, 4) void gs_mml(
    const unsigned short* __restrict__ X1h, const unsigned short* __restrict__ X1l,
    const unsigned short* __restrict__ W1h, const unsigned short* __restrict__ W1l,
    const unsigned short* __restrict__ X2h, const unsigned short* __restrict__ X2l,
    const unsigned short* __restrict__ W2h, const unsigned short* __restrict__ W2l,
    const void* __restrict__ bias, const int* __restrict__ flags,
    float* __restrict__ outf, unsigned short* __restrict__ outh,
    unsigned short* __restrict__ outl, int do_relu) {
    __shared__ __align__(16) unsigned char sm[65536];
    unsigned char* smXH = sm;            // 16 KB
    unsigned char* smXL = sm + 16384;    // 16 KB
    unsigned char* smWH = sm + 32768;    // 16 KB
    unsigned char* smWL = sm + 49152;    // 16 KB
    const bool isbf = flags[0] > 128;  // W lo plane is zero -> skip
    const int t = threadIdx.x;
    const int r0 = (int)blockIdx.x * 128;
    const int l = t & 63;
    const int wv = t >> 6;                // 0..7
    const int wr = wv >> 1, wc = wv & 1;  // 4x2 wave grid
    const int lr = l & 15, lg = l >> 4;

    floatx4 acc[2][4];
#pragma unroll
    for (int rt = 0; rt < 2; ++rt)
#pragma unroll
        for (int ct = 0; ct < 4; ++ct) acc[rt][ct] = (floatx4){0.f, 0.f, 0.f, 0.f};

    const int plane = wv >> 1;  // 0:XH 1:XL 2:WH 3:WL

    for (int ch = 0; ch < 4; ++ch) {
        const unsigned short* xh = (ch < 2) ? X1h : X2h;
        const unsigned short* xl = (ch < 2) ? X1l : X2l;
        const unsigned short* wh = (ch < 2) ? W1h : W2h;
        const unsigned short* wl = (ch < 2) ? W1l : W2l;
        const int ck0b = (ch & 1) << 7;  // k-chunk byte offset (64 bf16 = 128 B)

        __syncthreads();
        // stage 64KB via gld16: each wave fills 8KB of its plane (pair of waves per plane)
#pragma unroll
        for (int i = 0; i < 8; ++i) {
            const int q = ((wv & 1) << 13) + (i << 10) + (l << 4);  // within-plane byte
            const int rc = q >> 7;
            const int g16 = q & 0x7F;
            const int off = g16 ^ ((rc & 7) << 4);
            if (plane == 0) {
                const int gr = (r0 + rc < NN) ? (r0 + rc) : (NN - 1);
                gld16((const unsigned char*)xh + (size_t)gr * 256 + ck0b + off, smXH + q);
            } else if (plane == 1) {
                const int gr = (r0 + rc < NN) ? (r0 + rc) : (NN - 1);
                gld16((const unsigned char*)xl + (size_t)gr * 256 + ck0b + off, smXL + q);
            } else if (plane == 2) {
                gld16((const unsigned char*)wh + (size_t)rc * 256 + ck0b + off, smWH + q);
            } else if (!isbf) {
                gld16((const unsigned char*)wl + (size_t)rc * 256 + ck0b + off, smWL + q);
            }
        }
        __syncthreads();  // drains vmcnt(0)

        // compute: 2 k-steps x (2 row-tiles x 4 col-tiles) x split terms
#pragma unroll
        for (int ks = 0; ks < 2; ++ks) {
            const int kbyte = (ks << 6) + (lg << 4);
            short8v ah[2], al[2];
#pragma unroll
            for (int rt = 0; rt < 2; ++rt) {
                const int row = wr * 32 + rt * 16 + lr;
                const int off = (row << 7) + (kbyte ^ ((row & 7) << 4));
                ah[rt] = *(const short8v*)(smXH + off);
                al[rt] = *(const short8v*)(smXL + off);
            }
#pragma unroll
            for (int ct = 0; ct < 4; ++ct) {
                const int col = wc * 64 + ct * 16 + lr;
                const int boff = (col << 7) + (kbyte ^ ((col & 7) << 4));
                short8v bh = *(const short8v*)(smWH + boff);
                acc[0][ct] = mfma_bf16_16x16x32(ah[0], bh, acc[0][ct]);
                acc[1][ct] = mfma_bf16_16x16x32(ah[1], bh, acc[1][ct]);
                acc[0][ct] = mfma_bf16_16x16x32(al[0], bh, acc[0][ct]);
                acc[1][ct] = mfma_bf16_16x16x32(al[1], bh, acc[1][ct]);
                if (!isbf) {
                    short8v bl = *(const short8v*)(smWL + boff);
                    acc[0][ct] = mfma_bf16_16x16x32(ah[0], bl, acc[0][ct]);
                    acc[1][ct] = mfma_bf16_16x16x32(ah[1], bl, acc[1][ct]);
                }
            }
        }
    }

    // epilogue
#pragma unroll
    for (int ct = 0; ct < 4; ++ct) {
        const int col = wc * 64 + ct * 16 + lr;
        const float bbv = loadf(bias, col, isbf);
#pragma unroll
        for (int rt = 0; rt < 2; ++rt) {
#pragma unroll
            for (int rr = 0; rr < 4; ++rr) {
                const int row = r0 + wr * 32 + rt * 16 + (lg << 2) + rr;
                if (row < NN) {
                    float v = acc[rt][ct][rr] + bbv;
                    if (do_relu) v = v > 0.f ? v : 0.f;
                    if (outf) {
                        outf[(size_t)row * EMB + col] = v;
                    } else {
                        unsigned short h = f2us(v);
                        outh[(size_t)row * EMB + col] = h;
                        outl[(size_t)row * EMB + col] = f2us(v - us2f(h));
                    }
                }
            }
        }
    }
}

extern "C" __attribute__((visibility("default"))) void kernel_launch(
    void* const* d_in, const int* in_sizes, int n_in, void* d_out, int out_size, void* d_ws,
    size_t ws_size, hipStream_t stream) {
    // ---- ordering + dtype from in_sizes[0] (d_features in dict order, W_d if sorted) ----
    int iDF = 0, iMF = 1, iSRC = 2, iDST = 3, iWD = 4, iBD = 5, iWM = 6, iBM = 7;
    int iWS1 = 8, iWN1 = 9, iB1 = 10, iWS2 = 11, iWN2 = 12, iB2 = 13;
    long u0 = in_sizes ? (long)in_sizes[0] : 9575000L;
    int dt = -1;  // -1 unknown (probe), 0 f32, 1 bf16
    if (u0 == 49024L || u0 == 98048L || u0 == 196096L) {
        iWD = 0; iWM = 1; iWN1 = 2; iWN2 = 3; iWS1 = 4; iWS2 = 5;
        iB1 = 6; iB2 = 7; iBD = 8; iBM = 9; iDF = 10; iDST = 11; iMF = 12; iSRC = 13;
        if (u0 == 98048L) dt = 1;
        else if (u0 == 196096L) dt = 0;
    } else {
        if (u0 == 19150000L) dt = 1;       // bytes, bf16
        else if (u0 == 38300000L) dt = 0;  // bytes, f32
    }
    const void* d_features = d_in[iDF];
    const void* m_features = d_in[iMF];
    const int* src = (const int*)d_in[iSRC];
    const int* dst = (const int*)d_in[iDST];
    const void* W_d = d_in[iWD];
    const void* b_d = d_in[iBD];
    const void* W_m = d_in[iWM];
    const void* b_m = d_in[iBM];
    const void* W_self1 = d_in[iWS1];
    const void* W_neigh1 = d_in[iWN1];
    const void* b1 = d_in[iB1];
    const void* W_self2 = d_in[iWS2];
    const void* W_neigh2 = d_in[iWN2];
    const void* b2v = d_in[iB2];

    // ---- workspace layout (54,921,344 B — identical total to round 7) ----
    char* w = (char*)d_ws;
    int* flags = (int*)(w + 0);            //        64 B
    int* counts = (int*)(w + 64);          //   200,000 B
    int* row_start = (int*)(w + 200064);   //   200,004 B (pad to 400128)
    int* cursor = (int*)(w + 400128);      //   200,000 B
    int* bsums = (int*)(w + 600128);       //       256 B
    int* eidx = (int*)(w + 600384);        // 2,400,000 B (pad to 3000448)
    unsigned short* wt = (unsigned short*)(w + 3000448);  // 720,896 B split-bf16 WT panels
    unsigned short* wt_hd = wt + 0;
    unsigned short* wt_ld = wt + 49152;
    unsigned short* wt_hm = wt + 98304;
    unsigned short* wt_lm = wt + 163840;
    unsigned short* wt_hs1 = wt + 229376;
    unsigned short* wt_ls1 = wt + 245760;
    unsigned short* wt_hn1 = wt + 262144;
    unsigned short* wt_ln1 = wt + 278528;
    unsigned short* wt_hs2 = wt + 294912;
    unsigned short* wt_ls2 = wt + 311296;
    unsigned short* wt_hn2 = wt + 327680;
    unsigned short* wt_ln2 = wt + 344064;
    // hF / h1F as split bf16 plane pairs (12.8 MB each plane)
    unsigned short* hFh = (unsigned short*)(w + 3721344);    // 12,800,000 B
    unsigned short* hFl = (unsigned short*)(w + 16521344);   // 12,800,000 B
    unsigned short* h1Fh = (unsigned short*)(w + 29321344);  // 12,800,000 B
    unsigned short* h1Fl = (unsigned short*)(w + 42121344);  // 12,800,000 B -> 54,921,344
    // agg planes: agg1 -> d_out (dead before final write); agg2 -> hF region (dead after L1)
    unsigned short* ag1h = (unsigned short*)d_out;
    unsigned short* ag1l = ag1h + 6400000;
    unsigned short* ag2h = hFh;
    unsigned short* ag2l = hFl;

    const int NB_SCAN = (NN + 1023) / 1024;  // 49
    const int EB = (E_NUM + 255) / 256;      // 2344
    const int ZB = (NN + 255) / 256;         // 196

    // init + dtype resolution (flags[0] > 128 => bf16)
    hipLaunchKernelGGL(gs_zero, dim3(ZB), dim3(256), 0, stream, counts, flags);
    if (dt == 1)
        hipLaunchKernelGGL(gs_setflag, dim3(1), dim3(64), 0, stream, flags, 1000);
    else if (dt == 0)
        hipLaunchKernelGGL(gs_setflag, dim3(1), dim3(64), 0, stream, flags, 0);
    else
        hipLaunchKernelGGL(gs_probe, dim3(1), dim3(256), 0, stream, d_features, flags);

    // weight prep
    hipLaunchKernelGGL(gs_prepw, dim3(24), dim3(256), 0, stream, W_d, W_m, W_self1, W_neigh1,
                       W_self2, W_neigh2, flags, wt);

    // CSR build
    hipLaunchKernelGGL(gs_count, dim3(EB), dim3(256), 0, stream, dst, counts);
    hipLaunchKernelGGL(gs_scan1, dim3(NB_SCAN), dim3(256), 0, stream, counts, row_start, bsums);
    hipLaunchKernelGGL(gs_scan2, dim3(1), dim3(64), 0, stream, bsums, row_start, NB_SCAN);
    hipLaunchKernelGGL(gs_scan3, dim3(NB_SCAN), dim3(256), 0, stream, row_start, cursor, bsums);
    hipLaunchKernelGGL(gs_scatter, dim3(EB), dim3(256), 0, stream, src, dst, cursor, eidx);

    // projections (one dispatch, block-split) -> hF planes
    const int PBd = (N_DIS + 63) / 64;  // 391
    hipLaunchKernelGGL(gs_mmp, dim3(2 * PBd), dim3(256), 0, stream,
                       d_features, 383, wt_hd, wt_ld, 384, b_d,
                       m_features, 495, wt_hm, wt_lm, 512, b_m,
                       PBd, N_DIS, N_MIR, flags, hFh, hFl);

    const int AB = NN / 8;                 // 6250
    const int GBL = (NN + 127) / 128;      // 391

    // layer 1: agg(hF planes) -> d_out planes; h1F planes = relu(hF@Ws1 + agg@Wn1 + b1)
    hipLaunchKernelGGL(gs_aggp, dim3(AB), dim3(256), 0, stream, hFh, hFl, row_start, eidx,
                       ag1h, ag1l);
    hipLaunchKernelGGL(gs_mml, dim3(GBL), dim3(512), 0, stream,
                       hFh, hFl, wt_hs1, wt_ls1, ag1h, ag1l, wt_hn1, wt_ln1,
                       b1, flags, (float*)nullptr, h1Fh, h1Fl, 1);

    // layer 2: agg(h1F planes) -> hF region planes; d_out = h1F@Ws2 + agg@Wn2 + b2 (f32)
    hipLaunchKernelGGL(gs_aggp, dim3(AB), dim3(256), 0, stream, h1Fh, h1Fl, row_start, eidx,
                       ag2h, ag2l);
    hipLaunchKernelGGL(gs_mml, dim3(GBL), dim3(512), 0, stream,
                       h1Fh, h1Fl, wt_hs2, wt_ls2, ag2h, ag2l, wt_hn2, wt_ln2,
                       b2v, flags, (float*)d_out, (unsigned short*)nullptr,
                       (unsigned short*)nullptr, 0);
}